// Round 3
// baseline (189.935 us; speedup 1.0000x reference)
//
#include <hip/hip_runtime.h>

#define N_WT_     10
#define WT_LEN_   512
#define FIR_TAPS_ 31
#define N_REFL_   15
#define B_        16
#define L_        160000

constexpr int   TPB   = 256;
constexpr int   TSC   = 128;           // scan block size
constexpr float INCF  = 0.032f;        // f32(512/16000), jax weak-typed scalar
constexpr int   NG0   = L_ / 16;       // 10000 level-0 groups (of 16 samples)
constexpr int   NG1   = NG0 / 16;      // 625 level-1 groups
constexpr int   NG2   = 40;            // ceil(625/16), pad 625->640
constexpr int   NG3   = 3;             // ceil(40/16),  pad 40->48
constexpr int   WROW  = 20;            // paired-row table width (floats)

// ---------------------------------------------------------------------------
// Kernel 1: level-0 group sums y[g] (sequential f32 fold of 16 increments)
// PLUS level-1 sums z[j] (16-lane shuffle fold, same sequential association
// as the old scan's in-LDS fold). FIR filter fused into the first 10 blocks
// of row b==0; output is the PAIR-ROW table wt3[r][0..19] = [row r | row r+1
// mod 512], 80 B per row, 16B-aligned -> synth gathers 5x float4.
// ---------------------------------------------------------------------------
__global__ __launch_bounds__(TPB) void ysum_kernel(
        const float* __restrict__ pitch, float* __restrict__ y,
        float* __restrict__ z,
        const float* __restrict__ wavetables, const float* __restrict__ fir_h,
        float* __restrict__ wt3) {
    __shared__ float s_pad[WT_LEN_ + 2 * N_REFL_];
    __shared__ float s_h[FIR_TAPS_];
    const int b = blockIdx.y, bx = blockIdx.x, t = threadIdx.x;

    const bool do_fir = (b == 0) && (bx < N_WT_);   // uniform per block
    if (do_fir) {
        if (t < FIR_TAPS_) s_h[t] = fir_h[t];
        for (int j = t; j < WT_LEN_ + 2 * N_REFL_; j += TPB) {
            int src = (j + WT_LEN_ - N_REFL_) % WT_LEN_;
            s_pad[j] = wavetables[bx * WT_LEN_ + src];
        }
        __syncthreads();   // block-uniform condition: safe
        for (int i = t; i < WT_LEN_; i += TPB) {   // i = t and t+256
            float acc = 0.0f;
#pragma unroll
            for (int tap = 0; tap < FIR_TAPS_; ++tap)
                acc = fmaf(s_h[tap], s_pad[i + tap], acc);
            wt3[i * WROW + bx] = acc;                        // row i, cols 0-9
            wt3[((i + 511) & 511) * WROW + 10 + bx] = acc;   // "hi" copy, cols 10-19
        }
    }

    const int g = bx * 256 + t;
    const bool valid = (g < NG0);
    float acc = 0.0f;
    if (valid) {
        const float4* p4 = (const float4*)(pitch + (size_t)b * L_ + (size_t)g * 16);
        float4 v0 = p4[0], v1 = p4[1], v2 = p4[2], v3 = p4[3];
        float xs[16] = {v0.x, v0.y, v0.z, v0.w, v1.x, v1.y, v1.z, v1.w,
                        v2.x, v2.y, v2.z, v2.w, v3.x, v3.y, v3.z, v3.w};
#pragma unroll
        for (int i = 0; i < 16; ++i) {
            float inc = INCF * xs[i];
            asm("" : "+v"(inc));       // forbid mul+add contraction
            acc += inc;                // sequential f32 fold
        }
        y[b * NG0 + g] = acc;
    }

    // level-1 sums: sequential fold of the 16 group sums (lanes sbase..sbase+15)
    const int lane = t & 63, r16 = lane & 15, sbase = lane & ~15;
    float zacc = 0.0f;
#pragma unroll
    for (int k = 0; k < 16; ++k) {
        float v = __shfl(acc, sbase + k, 64);
        zacc += v;                     // same association as old scan's z fold
    }
    if (r16 == 15 && valid) z[b * NG1 + (g >> 4)] = zacc;
}

// ---------------------------------------------------------------------------
// Kernel 2: per-row prefix over the 625 level-1 sums only (levels 625->40->3),
// identical fold structure to the old scan's upper levels. S1 is no longer
// materialized; synth reconstructs it (bit-identically) from y and S2.
// ---------------------------------------------------------------------------
__global__ __launch_bounds__(TSC) void scan_kernel(
        const float* __restrict__ z, float* __restrict__ S2) {
    __shared__ float s_z[NG1];
    __shared__ float s_S2[NG1];
    __shared__ float s_w[NG2], s_S3[NG2];
    __shared__ float s_v[NG3], s_S4[NG3];
    const int b = blockIdx.x, t = threadIdx.x;
    const float* zrow = z + (size_t)b * NG1;
    for (int i = t; i < NG1; i += TSC) s_z[i] = zrow[i];
    __syncthreads();
    if (t < NG2) {
        float a = 0.0f;
        int hi = min(16 * t + 16, NG1);
        for (int i = 16 * t; i < hi; ++i) a += s_z[i];
        s_w[t] = a;
    }
    __syncthreads();
    if (t < NG3) {
        float a = 0.0f;
        int hi = min(16 * t + 16, NG2);
        for (int i = 16 * t; i < hi; ++i) a += s_w[i];
        s_v[t] = a;
    }
    __syncthreads();
    if (t == 0) {
        float run = 0.0f;
        for (int m = 0; m < NG3; ++m) { run += s_v[m]; s_S4[m] = run; }
    }
    __syncthreads();
    if (t < NG2) {
        float a = 0.0f;
        for (int i = (t >> 4) << 4; i <= t; ++i) a += s_w[i];
        if (t >= 16) a = a + s_S4[(t >> 4) - 1];
        s_S3[t] = a;
    }
    __syncthreads();
    if (t < NG2) {
        float r = 0.0f;
        float carry = (t > 0) ? s_S3[t - 1] : 0.0f;
        int hi = min(16 * t + 16, NG1);
        for (int k = 16 * t; k < hi; ++k) {
            r += s_z[k];
            s_S2[k] = (t > 0) ? r + carry : r;
        }
    }
    __syncthreads();
    float* S2row = S2 + (size_t)b * NG1;
    for (int i = t; i < NG1; i += TSC) S2row[i] = s_S2[i];
}

// ---------------------------------------------------------------------------
// Kernel 3: synth — barrier-free, LDS-free, one sample per thread
// (grid 625 x 16; block cb == level-1 group cb). Carry reconstruction:
//   S1[g0-1] = rr + S2[ci], rr = sequential fold of y over the level-1
//   group containing g0-1 (own block for jj>=1; full previous block for
//   jj==0), ci = cb-1-(jj==0) — identical association to the old scan's
//   S1 fill loop. Wavetable gather: rows lo,lo+1 = 20 contiguous floats at
//   80B-aligned base in the pair-row table -> 5x float4 (half the L1 line
//   transactions of the 10x float2 version).
// ---------------------------------------------------------------------------
__global__ __launch_bounds__(TPB) void synth_kernel(
        const float* __restrict__ pitch,
        const float* __restrict__ envelope,
        const float* __restrict__ attention,
        const float* __restrict__ wt3,
        const float* __restrict__ y,
        const float* __restrict__ S2,
        float* __restrict__ out) {
    const int b = blockIdx.y, cb = blockIdx.x, t = threadIdx.x;
    const int    l = cb * TPB + t;
    const size_t g = (size_t)b * L_ + l;

    const int lane  = t & 63;
    const int r16   = lane & 15;
    const int sbase = lane & ~15;
    const int jj    = t >> 4;          // local level-1 slot, uniform per 16-lane grp

    // --- issue every independent global load up-front ---
    const float pv  = pitch[g];          // own increment source
    const float p0  = pitch[l];          // batch-row-0 quirk (increment[0])
    const float env = envelope[g];
    const float* yrow = y + (size_t)b * NG0;
    const float yown  = yrow[16 * cb + r16];
    const float yprev = (cb > 0) ? yrow[16 * cb - 16 + r16] : 0.0f;
    const int   ci    = cb - 1 - (jj == 0 ? 1 : 0);
    const float s2v   = (ci >= 0) ? S2[(size_t)b * NG1 + ci] : 0.0f;
    const float2* ap = (const float2*)(attention + g * (size_t)N_WT_);
    float2 a01 = ap[0], a23 = ap[1], a45 = ap[2], a67 = ap[3], a89 = ap[4];

    float x = INCF * pv;  // f32 increment, separately rounded
    // sequential in-group-of-16 fold via shuffles (bit-exact association;
    // +0.0f predicated adds exact: all partials > 0 since pitch >= 100 Hz)
    float acc = 0.0f;
#pragma unroll
    for (int k = 0; k < 16; ++k) {
        float v = __shfl(x, sbase + k, 64);
        acc += (k <= r16) ? v : 0.0f;
    }

    // carry reconstruction (replaces the S1[g0-1] load)
    const float ysel = (jj == 0) ? yprev : yown;   // uniform per 16-lane group
    const int   n    = (jj == 0) ? 16 : jj;
    float rr = 0.0f;
#pragma unroll
    for (int k = 0; k < 16; ++k) {
        float v = __shfl(ysel, sbase + k, 64);
        rr += (k < n) ? v : 0.0f;
    }
    if (!(cb == 0 && jj == 0)) {
        float S1prev = (ci >= 0) ? (rr + s2v) : rr;   // (r + carry) order as old scan
        acc = acc + S1prev;                           // single carry add as before
    }

    float idx = acc - INCF * p0;         // minus increment[0] (batch row 0)
    float r = fmodf(idx, 512.0f);        // lax.rem (exact for y=512)
    if (r < 0.0f) r += 512.0f;           // jnp.remainder sign fixup
    if (512.0f - r < 1e-5f) r = 0.0f;    // the reference's snap
    float fl = floorf(r);
    float alpha = r - fl;
    int lo = (int)fl;

    // rows lo, lo+1 = 20 contiguous floats at 80B-aligned base (pair-row table)
    const float4* pw = (const float4*)(wt3 + lo * WROW);
    float4 q0 = pw[0], q1 = pw[1], q2 = pw[2], q3 = pw[3], q4 = pw[4];
    float loV[10] = {q0.x, q0.y, q0.z, q0.w, q1.x, q1.y, q1.z, q1.w, q2.x, q2.y};
    float hiV[10] = {q2.z, q2.w, q3.x, q3.y, q3.z, q3.w, q4.x, q4.y, q4.z, q4.w};
    float a[10] = {a01.x, a01.y, a23.x, a23.y, a45.x, a45.y,
                   a67.x, a67.y, a89.x, a89.y};

    float a0 = 0.0f;
#pragma unroll
    for (int w = 0; w < N_WT_; ++w)
        a0 += a[w] * (loV[w] + alpha * (hiV[w] - loV[w]));
    out[g] = a0 * env;
}

// ---------------------------------------------------------------------------
extern "C" void kernel_launch(void* const* d_in, const int* in_sizes, int n_in,
                              void* d_out, int out_size, void* d_ws, size_t ws_size,
                              hipStream_t stream) {
    const float* pitch      = (const float*)d_in[0];  // (B, L, 1)
    const float* envelope   = (const float*)d_in[1];  // (B, L, 1)
    const float* attention  = (const float*)d_in[2];  // (B, L, 10)
    const float* wavetables = (const float*)d_in[3];  // (10, 512)
    const float* fir_h      = (const float*)d_in[4];  // (31,)
    float*       out        = (float*)d_out;          // (B, L, 1)

    char*  ws  = (char*)d_ws;
    float* wt3 = (float*)(ws);                  // 512*20*4 = 40960 B
    float* y   = (float*)(ws + 40960);          // 16*10000*4 = 640000 B
    float* z   = (float*)(ws + 40960 + 640000); // 16*625*4 = 40000 B
    float* S2  = (float*)(ws + 40960 + 640000 + 40000);  // 40000 B

    ysum_kernel<<<dim3(40, B_), dim3(TPB), 0, stream>>>(
        pitch, y, z, wavetables, fir_h, wt3);
    scan_kernel<<<dim3(B_), dim3(TSC), 0, stream>>>(z, S2);
    synth_kernel<<<dim3(NG1, B_), dim3(TPB), 0, stream>>>(
        pitch, envelope, attention, wt3, y, S2, out);
}